// Round 9
// baseline (414.649 us; speedup 1.0000x reference)
//
#include <hip/hip_runtime.h>
#include <math.h>
#include <float.h>
#include <limits.h>

#define BN      32768   // B*N query rows
#define D_IN    1024
#define E_DIM   128
#define CB_N    8192

typedef _Float16 f16x8 __attribute__((ext_vector_type(8)));
typedef _Float16 f16x4 __attribute__((ext_vector_type(4)));
typedef float    f32x4 __attribute__((ext_vector_type(4)));

// Workspace:
//   ph  : [CB_N/16][4][64][8] f16   2 MB  (ncb*256 hi, B-frag packed)
//   pl  : same                      2 MB
//   rph : [32*8][64][8] f16         0.25 MB (rp*64 hi, B-frag packed)
//   rpl : same                      0.25 MB

// ---------------------------------------------------------------------------
// Kernel 1 (fused packs): blocks [0,512) pack codebook, blocks [512,544)
// pack rp via LDS-staged coalesced loads. (validated r1-r8)
// ---------------------------------------------------------------------------
__global__ __launch_bounds__(256) void pack_all_kernel(
    const float* __restrict__ cb, _Float16* __restrict__ ph,
    _Float16* __restrict__ pl,
    const float* __restrict__ rp, _Float16* __restrict__ rph,
    _Float16* __restrict__ rpl) {
    __shared__ float L[16][129];
    __shared__ float R[32][132];
    const int t = threadIdx.x;
    const int b = blockIdx.x;

    if (b < 512) {
        const int g = b;
        const int c = t >> 4, p = t & 15;
        const float4 v0 = *(const float4*)&cb[(size_t)(g * 16 + c) * E_DIM + p * 8];
        const float4 v1 = *(const float4*)&cb[(size_t)(g * 16 + c) * E_DIM + p * 8 + 4];
        float ss = v0.x * v0.x + v0.y * v0.y + v0.z * v0.z + v0.w * v0.w
                 + v1.x * v1.x + v1.y * v1.y + v1.z * v1.z + v1.w * v1.w;
#pragma unroll
        for (int m = 1; m < 16; m <<= 1) ss += __shfl_xor(ss, m);
        const float inv = 256.0f / fmaxf(sqrtf(ss), 1e-12f);

        L[c][p * 8 + 0] = v0.x * inv; L[c][p * 8 + 1] = v0.y * inv;
        L[c][p * 8 + 2] = v0.z * inv; L[c][p * 8 + 3] = v0.w * inv;
        L[c][p * 8 + 4] = v1.x * inv; L[c][p * 8 + 5] = v1.y * inv;
        L[c][p * 8 + 6] = v1.z * inv; L[c][p * 8 + 7] = v1.w * inv;
        __syncthreads();

        const int kb = t >> 6, lane = t & 63;
        const int quad = (lane >> 4), col = lane & 15;
        f16x8 h, l;
#pragma unroll
        for (int j = 0; j < 8; ++j) {
            const float v = L[col][kb * 32 + quad * 8 + j];
            const _Float16 hv = (_Float16)v;
            h[j] = hv;
            l[j] = (_Float16)(v - (float)hv);
        }
        const size_t off = ((size_t)(g * 4 + kb) * 64 + lane) * 8;
        *(f16x8*)&ph[off] = h;
        *(f16x8*)&pl[off] = l;
    } else {
        const int kb = b - 512;
        const int r = t >> 3, c0 = (t & 7) * 16;
#pragma unroll
        for (int i = 0; i < 4; ++i)
            *(float4*)&R[r][c0 + i * 4] =
                *(const float4*)&rp[(size_t)(kb * 32 + r) * E_DIM + c0 + i * 4];
        __syncthreads();

        const int w = t >> 6, lane = t & 63;
        const int quad = lane >> 4, col = lane & 15;
#pragma unroll
        for (int h2 = 0; h2 < 2; ++h2) {
            const int nt = w * 2 + h2;
            f16x8 hh, ll;
#pragma unroll
            for (int j = 0; j < 8; ++j) {
                const float v = R[quad * 8 + j][nt * 16 + col] * 64.0f;
                const _Float16 hv = (_Float16)v;
                hh[j] = hv;
                ll[j] = (_Float16)(v - (float)hv);
            }
            const size_t off = ((size_t)((kb * 8 + nt) * 64) + lane) * 8;
            *(f16x8*)&rph[off] = hh;
            *(f16x8*)&rpl[off] = ll;
        }
    }
}

// ---------------------------------------------------------------------------
// Kernel 2 (r9): champion R1 base (Qtile=64, 256 thr, 512 blocks, fused
// 263 us) with ONE change: phase-2 accumulators split per pass ->
// 6 independent MFMA chains of depth 4 per wave (was 2 chains of depth 12).
// Round-robin issue (kb-outer, pass-inner) maximizes chain interleave.
// Theory: dependent-MFMA latency at 2 waves/SIMD x 2 chains was the binder
// (4 chains/SIMD undersupplies the matrix pipe -> 40% MfmaUtil everywhere).
// Phase 1: barrier-free direct-from-global proj (r1-validated, 8 chains
// already). Argmax/merge identical to r1.
// ---------------------------------------------------------------------------
#define PPITCH  132   // phase-2 proj buffer row pitch (dwords), 528 B 16B-aligned

__global__ __launch_bounds__(256, 2) void fused_kernel(
    const float* __restrict__ x,
    const _Float16* __restrict__ rph, const _Float16* __restrict__ rpl,
    const _Float16* __restrict__ ph, const _Float16* __restrict__ pl,
    int* __restrict__ out) {
    __shared__ float    P[64 * PPITCH];
    __shared__ float    ls[4][32];
    __shared__ int      li[4][32];

    const int tid  = threadIdx.x;
    const int lane = tid & 63;
    const int w    = tid >> 6;
    const int quad = lane >> 4, col = lane & 15;
    const int qb   = blockIdx.x * 64;

    // ======================= Phase 1: projection (LDS-free) =================
    const float* xr[4];
#pragma unroll
    for (int mt = 0; mt < 4; ++mt)
        xr[mt] = x + (size_t)(qb + mt * 16 + col) * D_IN + quad * 8;

    f32x4 acc[4][2];
#pragma unroll
    for (int mt = 0; mt < 4; ++mt)
#pragma unroll
        for (int h = 0; h < 2; ++h) acc[mt][h] = (f32x4){0.f, 0.f, 0.f, 0.f};

    // A raw prefetch (kb=0)
    float4 pA[4][2];
#pragma unroll
    for (int mt = 0; mt < 4; ++mt) {
        pA[mt][0] = *(const float4*)(xr[mt] + 0);
        pA[mt][1] = *(const float4*)(xr[mt] + 4);
    }
    // B prefetch (kb=0)
    f16x8 bhc[2], blc[2];
#pragma unroll
    for (int h = 0; h < 2; ++h) {
        const size_t off = ((size_t)(w * 2 + h) * 64 + lane) * 8;
        bhc[h] = *(const f16x8*)&rph[off];
        blc[h] = *(const f16x8*)&rpl[off];
    }

    for (int kb = 0; kb < 32; ++kb) {
        // split current A into hi/lo frags
        f16x8 ah1[4], al1[4];
#pragma unroll
        for (int mt = 0; mt < 4; ++mt) {
            const float vv[8] = {pA[mt][0].x, pA[mt][0].y, pA[mt][0].z, pA[mt][0].w,
                                 pA[mt][1].x, pA[mt][1].y, pA[mt][1].z, pA[mt][1].w};
            f16x8 hh, ll;
#pragma unroll
            for (int j = 0; j < 8; ++j) {
                const float v = vv[j] * 512.0f;
                const _Float16 hv = (_Float16)v;
                hh[j] = hv;
                ll[j] = (_Float16)(v - (float)hv);
            }
            ah1[mt] = hh;
            al1[mt] = ll;
        }

        // prefetch next-kb A
        if (kb + 1 < 32) {
#pragma unroll
            for (int mt = 0; mt < 4; ++mt) {
                pA[mt][0] = *(const float4*)(xr[mt] + (kb + 1) * 32);
                pA[mt][1] = *(const float4*)(xr[mt] + (kb + 1) * 32 + 4);
            }
        }

        // current B, prefetch next-kb B
        f16x8 bh1[2] = {bhc[0], bhc[1]};
        f16x8 bl1[2] = {blc[0], blc[1]};
        if (kb + 1 < 32) {
#pragma unroll
            for (int h = 0; h < 2; ++h) {
                const size_t off = ((size_t)((kb + 1) * 8 + w * 2 + h) * 64 + lane) * 8;
                bhc[h] = *(const f16x8*)&rph[off];
                blc[h] = *(const f16x8*)&rpl[off];
            }
        }

#pragma unroll
        for (int mt = 0; mt < 4; ++mt)
#pragma unroll
            for (int h = 0; h < 2; ++h)
                acc[mt][h] = __builtin_amdgcn_mfma_f32_16x16x32_f16(ah1[mt], bh1[h], acc[mt][h], 0, 0, 0);
#pragma unroll
        for (int mt = 0; mt < 4; ++mt)
#pragma unroll
            for (int h = 0; h < 2; ++h)
                acc[mt][h] = __builtin_amdgcn_mfma_f32_16x16x32_f16(ah1[mt], bl1[h], acc[mt][h], 0, 0, 0);
#pragma unroll
        for (int mt = 0; mt < 4; ++mt)
#pragma unroll
            for (int h = 0; h < 2; ++h)
                acc[mt][h] = __builtin_amdgcn_mfma_f32_16x16x32_f16(al1[mt], bh1[h], acc[mt][h], 0, 0, 0);
    }

    // Write proj*16 (f32) to LDS transpose buffer [query][k].
    // C/D: row(query) = mt*16 + quad*4 + r, col(k) = w*32 + h*16 + (lane&15).
#pragma unroll
    for (int mt = 0; mt < 4; ++mt)
#pragma unroll
        for (int h = 0; h < 2; ++h)
#pragma unroll
            for (int r = 0; r < 4; ++r) {
                const int row = mt * 16 + quad * 4 + r;
                const int cc  = w * 32 + h * 16 + col;
                P[row * PPITCH + cc] = acc[mt][h][r] * (1.0f / 2048.0f);
            }
    __syncthreads();

    // ======================= Phase 2: scores + argmax =======================
    const int wq = w >> 1;   // query half: m-tiles wq*2, wq*2+1
    const int wc = w & 1;    // code half: tiles [wc*256, wc*256+256)

    // A frags from LDS: A[m=col][k=quad*8+j], split hi/lo.
    f16x8 ah[2][4], al[2][4];
#pragma unroll
    for (int mt2 = 0; mt2 < 2; ++mt2)
#pragma unroll
        for (int kb = 0; kb < 4; ++kb) {
            const int base = (wq * 32 + mt2 * 16 + col) * PPITCH + kb * 32 + quad * 8;
            const float4 v0 = *(const float4*)&P[base];
            const float4 v1 = *(const float4*)&P[base + 4];
            const float vv[8] = {v0.x, v0.y, v0.z, v0.w, v1.x, v1.y, v1.z, v1.w};
            f16x8 hh, ll;
#pragma unroll
            for (int j = 0; j < 8; ++j) {
                const _Float16 hv = (_Float16)vv[j];
                hh[j] = hv;
                ll[j] = (_Float16)(vv[j] - (float)hv);
            }
            ah[mt2][kb] = hh;
            al[mt2][kb] = ll;
        }

    float bs[8];
    int   bi[8];
#pragma unroll
    for (int s = 0; s < 8; ++s) { bs[s] = -FLT_MAX; bi[s] = 0; }

    const int g0 = wc * 256;

    // B double buffer in registers.
    f16x8 bh[2][4], bl[2][4];
#pragma unroll
    for (int kb = 0; kb < 4; ++kb) {
        const size_t off = ((size_t)(g0 * 4 + kb) * 64 + lane) * 8;
        bh[0][kb] = *(const f16x8*)&ph[off];
        bl[0][kb] = *(const f16x8*)&pl[off];
    }

#pragma unroll 2
    for (int t = 0; t < 256; ++t) {
        const int cur = t & 1, nxt = cur ^ 1;
        if (t + 1 < 256) {
            const int gn = g0 + t + 1;
#pragma unroll
            for (int kb = 0; kb < 4; ++kb) {
                const size_t off = ((size_t)(gn * 4 + kb) * 64 + lane) * 8;
                bh[nxt][kb] = *(const f16x8*)&ph[off];
                bl[nxt][kb] = *(const f16x8*)&pl[off];
            }
        }

        // 6 independent accumulator chains (pass x m-tile), depth 4 each.
        f32x4 sa[2], sb[2], sc[2];
#pragma unroll
        for (int mt2 = 0; mt2 < 2; ++mt2) {
            sa[mt2] = (f32x4){0.f, 0.f, 0.f, 0.f};
            sb[mt2] = (f32x4){0.f, 0.f, 0.f, 0.f};
            sc[mt2] = (f32x4){0.f, 0.f, 0.f, 0.f};
        }

        __builtin_amdgcn_s_setprio(1);
#pragma unroll
        for (int kb = 0; kb < 4; ++kb) {
            sa[0] = __builtin_amdgcn_mfma_f32_16x16x32_f16(ah[0][kb], bh[cur][kb], sa[0], 0, 0, 0);
            sa[1] = __builtin_amdgcn_mfma_f32_16x16x32_f16(ah[1][kb], bh[cur][kb], sa[1], 0, 0, 0);
            sb[0] = __builtin_amdgcn_mfma_f32_16x16x32_f16(ah[0][kb], bl[cur][kb], sb[0], 0, 0, 0);
            sb[1] = __builtin_amdgcn_mfma_f32_16x16x32_f16(ah[1][kb], bl[cur][kb], sb[1], 0, 0, 0);
            sc[0] = __builtin_amdgcn_mfma_f32_16x16x32_f16(al[0][kb], bh[cur][kb], sc[0], 0, 0, 0);
            sc[1] = __builtin_amdgcn_mfma_f32_16x16x32_f16(al[1][kb], bh[cur][kb], sc[1], 0, 0, 0);
        }
        __builtin_amdgcn_s_setprio(0);

        const int code = (g0 + t) * 16 + col;
#pragma unroll
        for (int mt2 = 0; mt2 < 2; ++mt2)
#pragma unroll
            for (int r = 0; r < 4; ++r) {
                const float v = sa[mt2][r] + sb[mt2][r] + sc[mt2][r];
                const int s = mt2 * 4 + r;
                if (v > bs[s]) { bs[s] = v; bi[s] = code; }  // ascending codes: > keeps min idx
            }
    }

    // Reduce the 16 code-columns per query (lanes differ in low 4 bits).
#pragma unroll
    for (int s = 0; s < 8; ++s) {
#pragma unroll
        for (int m = 1; m < 16; m <<= 1) {
            const float os = __shfl_xor(bs[s], m);
            const int   oi = __shfl_xor(bi[s], m);
            if (os > bs[s] || (os == bs[s] && oi < bi[s])) { bs[s] = os; bi[s] = oi; }
        }
    }

    if (col == 0) {
#pragma unroll
        for (int mt2 = 0; mt2 < 2; ++mt2)
#pragma unroll
            for (int r = 0; r < 4; ++r) {
                ls[w][mt2 * 16 + quad * 4 + r] = bs[mt2 * 4 + r];
                li[w][mt2 * 16 + quad * 4 + r] = bi[mt2 * 4 + r];
            }
    }
    __syncthreads();

    // Merge the two code halves (wc=0 codes < wc=1 codes: strict > keeps min idx).
    if (tid < 64) {
        const int q   = tid;
        const int wq2 = q >> 5;
        const int q32 = q & 31;
        float s = ls[wq2 * 2 + 0][q32];
        int   i = li[wq2 * 2 + 0][q32];
        const float os = ls[wq2 * 2 + 1][q32];
        if (os > s) { s = os; i = li[wq2 * 2 + 1][q32]; }
        out[qb + q] = i;
    }
}

// ---------------------------------------------------------------------------
extern "C" void kernel_launch(void* const* d_in, const int* in_sizes, int n_in,
                              void* d_out, int out_size, void* d_ws, size_t ws_size,
                              hipStream_t stream) {
    const float* x  = (const float*)d_in[0];   // [8,4096,1024]
    const float* rp = (const float*)d_in[1];   // [1024,128]
    const float* cb = (const float*)d_in[2];   // [8192,128]
    int* out = (int*)d_out;                    // [8,4096] int32

    _Float16* ph  = (_Float16*)d_ws;                         // 2 MB
    _Float16* pl  = ph  + (size_t)CB_N * E_DIM;              // 2 MB
    _Float16* rph = pl  + (size_t)CB_N * E_DIM;              // 256 KB
    _Float16* rpl = rph + (size_t)D_IN * E_DIM;              // 256 KB

    pack_all_kernel<<<CB_N / 16 + 32, 256, 0, stream>>>(cb, ph, pl, rp, rph, rpl);
    fused_kernel<<<BN / 64, 256, 0, stream>>>(x, rph, rpl, ph, pl, out);
}

// Round 10
// 395.302 us; speedup vs baseline: 1.0489x; 1.0489x over previous
//
#include <hip/hip_runtime.h>
#include <math.h>
#include <float.h>
#include <limits.h>

#define BN      32768   // B*N query rows
#define D_IN    1024
#define E_DIM   128
#define CB_N    8192

typedef _Float16 f16x8 __attribute__((ext_vector_type(8)));
typedef _Float16 f16x4 __attribute__((ext_vector_type(4)));
typedef float    f32x4 __attribute__((ext_vector_type(4)));

// Workspace:
//   ph  : [CB_N/16][4][64][8] f16   2 MB  (ncb*256 hi, B-frag packed)
//   pl  : same                      2 MB
//   rph : [32*8][64][8] f16         0.25 MB (rp*64 hi, B-frag packed)
//   rpl : same                      0.25 MB

// ---------------------------------------------------------------------------
// Kernel 1 (fused packs): blocks [0,512) pack codebook, blocks [512,544)
// pack rp via LDS-staged coalesced loads. (validated r1-r9)
// ---------------------------------------------------------------------------
__global__ __launch_bounds__(256) void pack_all_kernel(
    const float* __restrict__ cb, _Float16* __restrict__ ph,
    _Float16* __restrict__ pl,
    const float* __restrict__ rp, _Float16* __restrict__ rph,
    _Float16* __restrict__ rpl) {
    __shared__ float L[16][129];
    __shared__ float R[32][132];
    const int t = threadIdx.x;
    const int b = blockIdx.x;

    if (b < 512) {
        const int g = b;
        const int c = t >> 4, p = t & 15;
        const float4 v0 = *(const float4*)&cb[(size_t)(g * 16 + c) * E_DIM + p * 8];
        const float4 v1 = *(const float4*)&cb[(size_t)(g * 16 + c) * E_DIM + p * 8 + 4];
        float ss = v0.x * v0.x + v0.y * v0.y + v0.z * v0.z + v0.w * v0.w
                 + v1.x * v1.x + v1.y * v1.y + v1.z * v1.z + v1.w * v1.w;
#pragma unroll
        for (int m = 1; m < 16; m <<= 1) ss += __shfl_xor(ss, m);
        const float inv = 256.0f / fmaxf(sqrtf(ss), 1e-12f);

        L[c][p * 8 + 0] = v0.x * inv; L[c][p * 8 + 1] = v0.y * inv;
        L[c][p * 8 + 2] = v0.z * inv; L[c][p * 8 + 3] = v0.w * inv;
        L[c][p * 8 + 4] = v1.x * inv; L[c][p * 8 + 5] = v1.y * inv;
        L[c][p * 8 + 6] = v1.z * inv; L[c][p * 8 + 7] = v1.w * inv;
        __syncthreads();

        const int kb = t >> 6, lane = t & 63;
        const int quad = (lane >> 4), col = lane & 15;
        f16x8 h, l;
#pragma unroll
        for (int j = 0; j < 8; ++j) {
            const float v = L[col][kb * 32 + quad * 8 + j];
            const _Float16 hv = (_Float16)v;
            h[j] = hv;
            l[j] = (_Float16)(v - (float)hv);
        }
        const size_t off = ((size_t)(g * 4 + kb) * 64 + lane) * 8;
        *(f16x8*)&ph[off] = h;
        *(f16x8*)&pl[off] = l;
    } else {
        const int kb = b - 512;
        const int r = t >> 3, c0 = (t & 7) * 16;
#pragma unroll
        for (int i = 0; i < 4; ++i)
            *(float4*)&R[r][c0 + i * 4] =
                *(const float4*)&rp[(size_t)(kb * 32 + r) * E_DIM + c0 + i * 4];
        __syncthreads();

        const int w = t >> 6, lane = t & 63;
        const int quad = lane >> 4, col = lane & 15;
#pragma unroll
        for (int h2 = 0; h2 < 2; ++h2) {
            const int nt = w * 2 + h2;
            f16x8 hh, ll;
#pragma unroll
            for (int j = 0; j < 8; ++j) {
                const float v = R[quad * 8 + j][nt * 16 + col] * 64.0f;
                const _Float16 hv = (_Float16)v;
                hh[j] = hv;
                ll[j] = (_Float16)(v - (float)hv);
            }
            const size_t off = ((size_t)((kb * 8 + nt) * 64) + lane) * 8;
            *(f16x8*)&rph[off] = hh;
            *(f16x8*)&rpl[off] = ll;
        }
    }
}

// ---------------------------------------------------------------------------
// Kernel 2 (r10): champion r1 base (Qtile=64, 256 thr, 512 blocks) with ONE
// structural change in phase 2: B-reuse x4. Each wave holds A-frags for ALL
// 4 m-tiles (64 queries, 128 VGPR) and scans a codebook QUARTER
// [w*2048, (w+1)*2048): 48 MFMAs per 8 KB B-tile (2x r1's 24), halving
// per-CU B traffic (29.5 -> 15 B/cy) and per-MFMA address/argmax overhead.
// Accumulation order per output is bit-identical to r1 (pass-major, kb asc).
// Phase 1: byte-identical to r1. Merge: 4-way ascending quarters (r8 logic).
// ---------------------------------------------------------------------------
#define PPITCH  132   // phase-2 proj buffer row pitch (dwords), 528 B 16B-aligned

__global__ __launch_bounds__(256, 2) void fused_kernel(
    const float* __restrict__ x,
    const _Float16* __restrict__ rph, const _Float16* __restrict__ rpl,
    const _Float16* __restrict__ ph, const _Float16* __restrict__ pl,
    int* __restrict__ out) {
    __shared__ float    P[64 * PPITCH];
    __shared__ float    ls[4][64];
    __shared__ int      li[4][64];

    const int tid  = threadIdx.x;
    const int lane = tid & 63;
    const int w    = tid >> 6;
    const int quad = lane >> 4, col = lane & 15;
    const int qb   = blockIdx.x * 64;

    // ======================= Phase 1: projection (LDS-free) =================
    const float* xr[4];
#pragma unroll
    for (int mt = 0; mt < 4; ++mt)
        xr[mt] = x + (size_t)(qb + mt * 16 + col) * D_IN + quad * 8;

    f32x4 acc[4][2];
#pragma unroll
    for (int mt = 0; mt < 4; ++mt)
#pragma unroll
        for (int h = 0; h < 2; ++h) acc[mt][h] = (f32x4){0.f, 0.f, 0.f, 0.f};

    // A raw prefetch (kb=0)
    float4 pA[4][2];
#pragma unroll
    for (int mt = 0; mt < 4; ++mt) {
        pA[mt][0] = *(const float4*)(xr[mt] + 0);
        pA[mt][1] = *(const float4*)(xr[mt] + 4);
    }
    // B prefetch (kb=0)
    f16x8 bhc[2], blc[2];
#pragma unroll
    for (int h = 0; h < 2; ++h) {
        const size_t off = ((size_t)(w * 2 + h) * 64 + lane) * 8;
        bhc[h] = *(const f16x8*)&rph[off];
        blc[h] = *(const f16x8*)&rpl[off];
    }

    for (int kb = 0; kb < 32; ++kb) {
        // split current A into hi/lo frags
        f16x8 ah1[4], al1[4];
#pragma unroll
        for (int mt = 0; mt < 4; ++mt) {
            const float vv[8] = {pA[mt][0].x, pA[mt][0].y, pA[mt][0].z, pA[mt][0].w,
                                 pA[mt][1].x, pA[mt][1].y, pA[mt][1].z, pA[mt][1].w};
            f16x8 hh, ll;
#pragma unroll
            for (int j = 0; j < 8; ++j) {
                const float v = vv[j] * 512.0f;
                const _Float16 hv = (_Float16)v;
                hh[j] = hv;
                ll[j] = (_Float16)(v - (float)hv);
            }
            ah1[mt] = hh;
            al1[mt] = ll;
        }

        // prefetch next-kb A
        if (kb + 1 < 32) {
#pragma unroll
            for (int mt = 0; mt < 4; ++mt) {
                pA[mt][0] = *(const float4*)(xr[mt] + (kb + 1) * 32);
                pA[mt][1] = *(const float4*)(xr[mt] + (kb + 1) * 32 + 4);
            }
        }

        // current B, prefetch next-kb B
        f16x8 bh1[2] = {bhc[0], bhc[1]};
        f16x8 bl1[2] = {blc[0], blc[1]};
        if (kb + 1 < 32) {
#pragma unroll
            for (int h = 0; h < 2; ++h) {
                const size_t off = ((size_t)((kb + 1) * 8 + w * 2 + h) * 64 + lane) * 8;
                bhc[h] = *(const f16x8*)&rph[off];
                blc[h] = *(const f16x8*)&rpl[off];
            }
        }

#pragma unroll
        for (int mt = 0; mt < 4; ++mt)
#pragma unroll
            for (int h = 0; h < 2; ++h)
                acc[mt][h] = __builtin_amdgcn_mfma_f32_16x16x32_f16(ah1[mt], bh1[h], acc[mt][h], 0, 0, 0);
#pragma unroll
        for (int mt = 0; mt < 4; ++mt)
#pragma unroll
            for (int h = 0; h < 2; ++h)
                acc[mt][h] = __builtin_amdgcn_mfma_f32_16x16x32_f16(ah1[mt], bl1[h], acc[mt][h], 0, 0, 0);
#pragma unroll
        for (int mt = 0; mt < 4; ++mt)
#pragma unroll
            for (int h = 0; h < 2; ++h)
                acc[mt][h] = __builtin_amdgcn_mfma_f32_16x16x32_f16(al1[mt], bh1[h], acc[mt][h], 0, 0, 0);
    }

    // Write proj*16 (f32) to LDS transpose buffer [query][k].
    // C/D: row(query) = mt*16 + quad*4 + r, col(k) = w*32 + h*16 + (lane&15).
#pragma unroll
    for (int mt = 0; mt < 4; ++mt)
#pragma unroll
        for (int h = 0; h < 2; ++h)
#pragma unroll
            for (int r = 0; r < 4; ++r) {
                const int row = mt * 16 + quad * 4 + r;
                const int cc  = w * 32 + h * 16 + col;
                P[row * PPITCH + cc] = acc[mt][h][r] * (1.0f / 2048.0f);
            }
    __syncthreads();

    // ======================= Phase 2: scores + argmax =======================
    // A frags from LDS: ALL 4 m-tiles, A[m=col][k=quad*8+j], split hi/lo.
    f16x8 ah[4][4], al[4][4];
#pragma unroll
    for (int mt = 0; mt < 4; ++mt)
#pragma unroll
        for (int kb = 0; kb < 4; ++kb) {
            const int base = (mt * 16 + col) * PPITCH + kb * 32 + quad * 8;
            const float4 v0 = *(const float4*)&P[base];
            const float4 v1 = *(const float4*)&P[base + 4];
            const float vv[8] = {v0.x, v0.y, v0.z, v0.w, v1.x, v1.y, v1.z, v1.w};
            f16x8 hh, ll;
#pragma unroll
            for (int j = 0; j < 8; ++j) {
                const _Float16 hv = (_Float16)vv[j];
                hh[j] = hv;
                ll[j] = (_Float16)(vv[j] - (float)hv);
            }
            ah[mt][kb] = hh;
            al[mt][kb] = ll;
        }

    float bs[16];
    int   bi[16];
#pragma unroll
    for (int s = 0; s < 16; ++s) { bs[s] = -FLT_MAX; bi[s] = 0; }

    // Wave w scans 16-code tiles [w*128, (w+1)*128) (codebook quarter).
    const int g0 = w * 128;

    // B double buffer in registers.
    f16x8 bh[2][4], bl[2][4];
#pragma unroll
    for (int kb = 0; kb < 4; ++kb) {
        const size_t off = ((size_t)(g0 * 4 + kb) * 64 + lane) * 8;
        bh[0][kb] = *(const f16x8*)&ph[off];
        bl[0][kb] = *(const f16x8*)&pl[off];
    }

#pragma unroll 2
    for (int t = 0; t < 128; ++t) {
        const int cur = t & 1, nxt = cur ^ 1;
        if (t + 1 < 128) {
            const int gn = g0 + t + 1;
#pragma unroll
            for (int kb = 0; kb < 4; ++kb) {
                const size_t off = ((size_t)(gn * 4 + kb) * 64 + lane) * 8;
                bh[nxt][kb] = *(const f16x8*)&ph[off];
                bl[nxt][kb] = *(const f16x8*)&pl[off];
            }
        }

        f32x4 sacc[4];
#pragma unroll
        for (int mt = 0; mt < 4; ++mt) sacc[mt] = (f32x4){0.f, 0.f, 0.f, 0.f};

        __builtin_amdgcn_s_setprio(1);
#pragma unroll
        for (int kb = 0; kb < 4; ++kb)
#pragma unroll
            for (int mt = 0; mt < 4; ++mt)
                sacc[mt] = __builtin_amdgcn_mfma_f32_16x16x32_f16(ah[mt][kb], bh[cur][kb], sacc[mt], 0, 0, 0);
#pragma unroll
        for (int kb = 0; kb < 4; ++kb)
#pragma unroll
            for (int mt = 0; mt < 4; ++mt)
                sacc[mt] = __builtin_amdgcn_mfma_f32_16x16x32_f16(ah[mt][kb], bl[cur][kb], sacc[mt], 0, 0, 0);
#pragma unroll
        for (int kb = 0; kb < 4; ++kb)
#pragma unroll
            for (int mt = 0; mt < 4; ++mt)
                sacc[mt] = __builtin_amdgcn_mfma_f32_16x16x32_f16(al[mt][kb], bh[cur][kb], sacc[mt], 0, 0, 0);
        __builtin_amdgcn_s_setprio(0);

        const int code = (g0 + t) * 16 + col;
#pragma unroll
        for (int mt = 0; mt < 4; ++mt)
#pragma unroll
            for (int r = 0; r < 4; ++r) {
                const float v = sacc[mt][r];
                const int s = mt * 4 + r;
                if (v > bs[s]) { bs[s] = v; bi[s] = code; }  // ascending codes: > keeps min idx
            }
    }

    // Reduce the 16 code-columns per query (lanes differ in low 4 bits).
#pragma unroll
    for (int s = 0; s < 16; ++s) {
#pragma unroll
        for (int m = 1; m < 16; m <<= 1) {
            const float os = __shfl_xor(bs[s], m);
            const int   oi = __shfl_xor(bi[s], m);
            if (os > bs[s] || (os == bs[s] && oi < bi[s])) { bs[s] = os; bi[s] = oi; }
        }
    }

    if (col == 0) {
#pragma unroll
        for (int mt = 0; mt < 4; ++mt)
#pragma unroll
            for (int r = 0; r < 4; ++r) {
                ls[w][mt * 16 + quad * 4 + r] = bs[mt * 4 + r];
                li[w][mt * 16 + quad * 4 + r] = bi[mt * 4 + r];
            }
    }
    __syncthreads();

    // Merge the 4 code quarters (wave 0 codes < wave 1 < ...: strict > keeps min idx).
    if (tid < 64) {
        const int q = tid;
        float s = ls[0][q];
        int   i = li[0][q];
#pragma unroll
        for (int ww = 1; ww < 4; ++ww) {
            const float os = ls[ww][q];
            if (os > s) { s = os; i = li[ww][q]; }
        }
        out[qb + q] = i;
    }
}

// ---------------------------------------------------------------------------
extern "C" void kernel_launch(void* const* d_in, const int* in_sizes, int n_in,
                              void* d_out, int out_size, void* d_ws, size_t ws_size,
                              hipStream_t stream) {
    const float* x  = (const float*)d_in[0];   // [8,4096,1024]
    const float* rp = (const float*)d_in[1];   // [1024,128]
    const float* cb = (const float*)d_in[2];   // [8192,128]
    int* out = (int*)d_out;                    // [8,4096] int32

    _Float16* ph  = (_Float16*)d_ws;                         // 2 MB
    _Float16* pl  = ph  + (size_t)CB_N * E_DIM;              // 2 MB
    _Float16* rph = pl  + (size_t)CB_N * E_DIM;              // 256 KB
    _Float16* rpl = rph + (size_t)D_IN * E_DIM;              // 256 KB

    pack_all_kernel<<<CB_N / 16 + 32, 256, 0, stream>>>(cb, ph, pl, rp, rph, rpl);
    fused_kernel<<<BN / 64, 256, 0, stream>>>(x, rph, rpl, ph, pl, out);
}

// Round 11
// 372.678 us; speedup vs baseline: 1.1126x; 1.0607x over previous
//
#include <hip/hip_runtime.h>
#include <math.h>
#include <float.h>
#include <limits.h>

#define BN      32768   // B*N query rows
#define D_IN    1024
#define E_DIM   128
#define CB_N    8192

typedef _Float16 f16x8 __attribute__((ext_vector_type(8)));
typedef _Float16 f16x4 __attribute__((ext_vector_type(4)));
typedef float    f32x4 __attribute__((ext_vector_type(4)));

// Workspace:
//   ph  : [CB_N/16][4][64][8] f16   2 MB  (ncb*256 hi, B-frag packed)
//   pl  : same                      2 MB
//   rph : [32*8][64][8] f16         0.25 MB (rp*64 hi, B-frag packed)
//   rpl : same                      0.25 MB

// ---------------------------------------------------------------------------
// Kernel 1 (fused packs): blocks [0,512) pack codebook, blocks [512,544)
// pack rp via LDS-staged coalesced loads. (validated r1-r10)
// ---------------------------------------------------------------------------
__global__ __launch_bounds__(256) void pack_all_kernel(
    const float* __restrict__ cb, _Float16* __restrict__ ph,
    _Float16* __restrict__ pl,
    const float* __restrict__ rp, _Float16* __restrict__ rph,
    _Float16* __restrict__ rpl) {
    __shared__ float L[16][129];
    __shared__ float R[32][132];
    const int t = threadIdx.x;
    const int b = blockIdx.x;

    if (b < 512) {
        const int g = b;
        const int c = t >> 4, p = t & 15;
        const float4 v0 = *(const float4*)&cb[(size_t)(g * 16 + c) * E_DIM + p * 8];
        const float4 v1 = *(const float4*)&cb[(size_t)(g * 16 + c) * E_DIM + p * 8 + 4];
        float ss = v0.x * v0.x + v0.y * v0.y + v0.z * v0.z + v0.w * v0.w
                 + v1.x * v1.x + v1.y * v1.y + v1.z * v1.z + v1.w * v1.w;
#pragma unroll
        for (int m = 1; m < 16; m <<= 1) ss += __shfl_xor(ss, m);
        const float inv = 256.0f / fmaxf(sqrtf(ss), 1e-12f);

        L[c][p * 8 + 0] = v0.x * inv; L[c][p * 8 + 1] = v0.y * inv;
        L[c][p * 8 + 2] = v0.z * inv; L[c][p * 8 + 3] = v0.w * inv;
        L[c][p * 8 + 4] = v1.x * inv; L[c][p * 8 + 5] = v1.y * inv;
        L[c][p * 8 + 6] = v1.z * inv; L[c][p * 8 + 7] = v1.w * inv;
        __syncthreads();

        const int kb = t >> 6, lane = t & 63;
        const int quad = (lane >> 4), col = lane & 15;
        f16x8 h, l;
#pragma unroll
        for (int j = 0; j < 8; ++j) {
            const float v = L[col][kb * 32 + quad * 8 + j];
            const _Float16 hv = (_Float16)v;
            h[j] = hv;
            l[j] = (_Float16)(v - (float)hv);
        }
        const size_t off = ((size_t)(g * 4 + kb) * 64 + lane) * 8;
        *(f16x8*)&ph[off] = h;
        *(f16x8*)&pl[off] = l;
    } else {
        const int kb = b - 512;
        const int r = t >> 3, c0 = (t & 7) * 16;
#pragma unroll
        for (int i = 0; i < 4; ++i)
            *(float4*)&R[r][c0 + i * 4] =
                *(const float4*)&rp[(size_t)(kb * 32 + r) * E_DIM + c0 + i * 4];
        __syncthreads();

        const int w = t >> 6, lane = t & 63;
        const int quad = lane >> 4, col = lane & 15;
#pragma unroll
        for (int h2 = 0; h2 < 2; ++h2) {
            const int nt = w * 2 + h2;
            f16x8 hh, ll;
#pragma unroll
            for (int j = 0; j < 8; ++j) {
                const float v = R[quad * 8 + j][nt * 16 + col] * 64.0f;
                const _Float16 hv = (_Float16)v;
                hh[j] = hv;
                ll[j] = (_Float16)(v - (float)hv);
            }
            const size_t off = ((size_t)((kb * 8 + nt) * 64) + lane) * 8;
            *(f16x8*)&rph[off] = hh;
            *(f16x8*)&rpl[off] = ll;
        }
    }
}

// ---------------------------------------------------------------------------
// Kernel 2 (r11): r10's B-reuse x4 (wave holds all 4 m-tiles, scans a
// codebook quarter; halved per-CU L2 demand) WITHOUT the register spill:
// B single-buffered (bh[4], bl[4]; saves 64 VGPRs vs r10's double buffer)
// with software-pipelined reloads enabled by pass reorder:
//   p1: ah x bh   p2: al x bh   [reload bh <- t+1]   p3: ah x bl   [argmax]
//   [reload bl <- t+1]
// bh prefetch distance ~310 cy (pass 3), bl ~620 cy (p1+p2) - both cover L2.
// Live set ~210 regs -> no spill at (256,2). Phase 1 / merge: r10-identical.
// ---------------------------------------------------------------------------
#define PPITCH  132   // phase-2 proj buffer row pitch (dwords), 528 B 16B-aligned

__global__ __launch_bounds__(256, 2) void fused_kernel(
    const float* __restrict__ x,
    const _Float16* __restrict__ rph, const _Float16* __restrict__ rpl,
    const _Float16* __restrict__ ph, const _Float16* __restrict__ pl,
    int* __restrict__ out) {
    __shared__ float    P[64 * PPITCH];
    __shared__ float    ls[4][64];
    __shared__ int      li[4][64];

    const int tid  = threadIdx.x;
    const int lane = tid & 63;
    const int w    = tid >> 6;
    const int quad = lane >> 4, col = lane & 15;
    const int qb   = blockIdx.x * 64;

    // ======================= Phase 1: projection (LDS-free) =================
    const float* xr[4];
#pragma unroll
    for (int mt = 0; mt < 4; ++mt)
        xr[mt] = x + (size_t)(qb + mt * 16 + col) * D_IN + quad * 8;

    f32x4 acc[4][2];
#pragma unroll
    for (int mt = 0; mt < 4; ++mt)
#pragma unroll
        for (int h = 0; h < 2; ++h) acc[mt][h] = (f32x4){0.f, 0.f, 0.f, 0.f};

    // A raw prefetch (kb=0)
    float4 pA[4][2];
#pragma unroll
    for (int mt = 0; mt < 4; ++mt) {
        pA[mt][0] = *(const float4*)(xr[mt] + 0);
        pA[mt][1] = *(const float4*)(xr[mt] + 4);
    }
    // B prefetch (kb=0)
    f16x8 bhc[2], blc[2];
#pragma unroll
    for (int h = 0; h < 2; ++h) {
        const size_t off = ((size_t)(w * 2 + h) * 64 + lane) * 8;
        bhc[h] = *(const f16x8*)&rph[off];
        blc[h] = *(const f16x8*)&rpl[off];
    }

    for (int kb = 0; kb < 32; ++kb) {
        // split current A into hi/lo frags
        f16x8 ah1[4], al1[4];
#pragma unroll
        for (int mt = 0; mt < 4; ++mt) {
            const float vv[8] = {pA[mt][0].x, pA[mt][0].y, pA[mt][0].z, pA[mt][0].w,
                                 pA[mt][1].x, pA[mt][1].y, pA[mt][1].z, pA[mt][1].w};
            f16x8 hh, ll;
#pragma unroll
            for (int j = 0; j < 8; ++j) {
                const float v = vv[j] * 512.0f;
                const _Float16 hv = (_Float16)v;
                hh[j] = hv;
                ll[j] = (_Float16)(v - (float)hv);
            }
            ah1[mt] = hh;
            al1[mt] = ll;
        }

        // prefetch next-kb A
        if (kb + 1 < 32) {
#pragma unroll
            for (int mt = 0; mt < 4; ++mt) {
                pA[mt][0] = *(const float4*)(xr[mt] + (kb + 1) * 32);
                pA[mt][1] = *(const float4*)(xr[mt] + (kb + 1) * 32 + 4);
            }
        }

        // current B, prefetch next-kb B
        f16x8 bh1[2] = {bhc[0], bhc[1]};
        f16x8 bl1[2] = {blc[0], blc[1]};
        if (kb + 1 < 32) {
#pragma unroll
            for (int h = 0; h < 2; ++h) {
                const size_t off = ((size_t)((kb + 1) * 8 + w * 2 + h) * 64 + lane) * 8;
                bhc[h] = *(const f16x8*)&rph[off];
                blc[h] = *(const f16x8*)&rpl[off];
            }
        }

#pragma unroll
        for (int mt = 0; mt < 4; ++mt)
#pragma unroll
            for (int h = 0; h < 2; ++h)
                acc[mt][h] = __builtin_amdgcn_mfma_f32_16x16x32_f16(ah1[mt], bh1[h], acc[mt][h], 0, 0, 0);
#pragma unroll
        for (int mt = 0; mt < 4; ++mt)
#pragma unroll
            for (int h = 0; h < 2; ++h)
                acc[mt][h] = __builtin_amdgcn_mfma_f32_16x16x32_f16(ah1[mt], bl1[h], acc[mt][h], 0, 0, 0);
#pragma unroll
        for (int mt = 0; mt < 4; ++mt)
#pragma unroll
            for (int h = 0; h < 2; ++h)
                acc[mt][h] = __builtin_amdgcn_mfma_f32_16x16x32_f16(al1[mt], bh1[h], acc[mt][h], 0, 0, 0);
    }

    // Write proj*16 (f32) to LDS transpose buffer [query][k].
    // C/D: row(query) = mt*16 + quad*4 + r, col(k) = w*32 + h*16 + (lane&15).
#pragma unroll
    for (int mt = 0; mt < 4; ++mt)
#pragma unroll
        for (int h = 0; h < 2; ++h)
#pragma unroll
            for (int r = 0; r < 4; ++r) {
                const int row = mt * 16 + quad * 4 + r;
                const int cc  = w * 32 + h * 16 + col;
                P[row * PPITCH + cc] = acc[mt][h][r] * (1.0f / 2048.0f);
            }
    __syncthreads();

    // ======================= Phase 2: scores + argmax =======================
    // A frags from LDS: ALL 4 m-tiles, A[m=col][k=quad*8+j], split hi/lo.
    f16x8 ah[4][4], al[4][4];
#pragma unroll
    for (int mt = 0; mt < 4; ++mt)
#pragma unroll
        for (int kb = 0; kb < 4; ++kb) {
            const int base = (mt * 16 + col) * PPITCH + kb * 32 + quad * 8;
            const float4 v0 = *(const float4*)&P[base];
            const float4 v1 = *(const float4*)&P[base + 4];
            const float vv[8] = {v0.x, v0.y, v0.z, v0.w, v1.x, v1.y, v1.z, v1.w};
            f16x8 hh, ll;
#pragma unroll
            for (int j = 0; j < 8; ++j) {
                const _Float16 hv = (_Float16)vv[j];
                hh[j] = hv;
                ll[j] = (_Float16)(vv[j] - (float)hv);
            }
            ah[mt][kb] = hh;
            al[mt][kb] = ll;
        }

    float bs[16];
    int   bi[16];
#pragma unroll
    for (int s = 0; s < 16; ++s) { bs[s] = -FLT_MAX; bi[s] = 0; }

    // Wave w scans 16-code tiles [w*128, (w+1)*128) (codebook quarter).
    const int g0 = w * 128;

    // B single-buffered, software-pipelined (see header comment).
    f16x8 bh[4], bl[4];
#pragma unroll
    for (int kb = 0; kb < 4; ++kb) {
        const size_t off = ((size_t)(g0 * 4 + kb) * 64 + lane) * 8;
        bh[kb] = *(const f16x8*)&ph[off];
        bl[kb] = *(const f16x8*)&pl[off];
    }

    for (int t = 0; t < 128; ++t) {
        f32x4 sacc[4];
#pragma unroll
        for (int mt = 0; mt < 4; ++mt) sacc[mt] = (f32x4){0.f, 0.f, 0.f, 0.f};

        // p1: ah x bh
        __builtin_amdgcn_s_setprio(1);
#pragma unroll
        for (int kb = 0; kb < 4; ++kb)
#pragma unroll
            for (int mt = 0; mt < 4; ++mt)
                sacc[mt] = __builtin_amdgcn_mfma_f32_16x16x32_f16(ah[mt][kb], bh[kb], sacc[mt], 0, 0, 0);
        // p2: al x bh  (bh dead after this pass)
#pragma unroll
        for (int kb = 0; kb < 4; ++kb)
#pragma unroll
            for (int mt = 0; mt < 4; ++mt)
                sacc[mt] = __builtin_amdgcn_mfma_f32_16x16x32_f16(al[mt][kb], bh[kb], sacc[mt], 0, 0, 0);
        __builtin_amdgcn_s_setprio(0);

        // reload bh <- tile t+1 (lands during p3, ~310 cy of MFMA)
        if (t + 1 < 128) {
            const int gn = g0 + t + 1;
#pragma unroll
            for (int kb = 0; kb < 4; ++kb) {
                const size_t off = ((size_t)(gn * 4 + kb) * 64 + lane) * 8;
                bh[kb] = *(const f16x8*)&ph[off];
            }
        }

        // p3: ah x bl  (bl dead after this pass)
        __builtin_amdgcn_s_setprio(1);
#pragma unroll
        for (int kb = 0; kb < 4; ++kb)
#pragma unroll
            for (int mt = 0; mt < 4; ++mt)
                sacc[mt] = __builtin_amdgcn_mfma_f32_16x16x32_f16(ah[mt][kb], bl[kb], sacc[mt], 0, 0, 0);
        __builtin_amdgcn_s_setprio(0);

        // reload bl <- tile t+1 (needed at t+1's p3: ~620 cy of cover)
        if (t + 1 < 128) {
            const int gn = g0 + t + 1;
#pragma unroll
            for (int kb = 0; kb < 4; ++kb) {
                const size_t off = ((size_t)(gn * 4 + kb) * 64 + lane) * 8;
                bl[kb] = *(const f16x8*)&pl[off];
            }
        }

        const int code = (g0 + t) * 16 + col;
#pragma unroll
        for (int mt = 0; mt < 4; ++mt)
#pragma unroll
            for (int r = 0; r < 4; ++r) {
                const float v = sacc[mt][r];
                const int s = mt * 4 + r;
                if (v > bs[s]) { bs[s] = v; bi[s] = code; }  // ascending codes: > keeps min idx
            }
    }

    // Reduce the 16 code-columns per query (lanes differ in low 4 bits).
#pragma unroll
    for (int s = 0; s < 16; ++s) {
#pragma unroll
        for (int m = 1; m < 16; m <<= 1) {
            const float os = __shfl_xor(bs[s], m);
            const int   oi = __shfl_xor(bi[s], m);
            if (os > bs[s] || (os == bs[s] && oi < bi[s])) { bs[s] = os; bi[s] = oi; }
        }
    }

    if (col == 0) {
#pragma unroll
        for (int mt = 0; mt < 4; ++mt)
#pragma unroll
            for (int r = 0; r < 4; ++r) {
                ls[w][mt * 16 + quad * 4 + r] = bs[mt * 4 + r];
                li[w][mt * 16 + quad * 4 + r] = bi[mt * 4 + r];
            }
    }
    __syncthreads();

    // Merge the 4 code quarters (wave 0 codes < wave 1 < ...: strict > keeps min idx).
    if (tid < 64) {
        const int q = tid;
        float s = ls[0][q];
        int   i = li[0][q];
#pragma unroll
        for (int ww = 1; ww < 4; ++ww) {
            const float os = ls[ww][q];
            if (os > s) { s = os; i = li[ww][q]; }
        }
        out[qb + q] = i;
    }
}

// ---------------------------------------------------------------------------
extern "C" void kernel_launch(void* const* d_in, const int* in_sizes, int n_in,
                              void* d_out, int out_size, void* d_ws, size_t ws_size,
                              hipStream_t stream) {
    const float* x  = (const float*)d_in[0];   // [8,4096,1024]
    const float* rp = (const float*)d_in[1];   // [1024,128]
    const float* cb = (const float*)d_in[2];   // [8192,128]
    int* out = (int*)d_out;                    // [8,4096] int32

    _Float16* ph  = (_Float16*)d_ws;                         // 2 MB
    _Float16* pl  = ph  + (size_t)CB_N * E_DIM;              // 2 MB
    _Float16* rph = pl  + (size_t)CB_N * E_DIM;              // 256 KB
    _Float16* rpl = rph + (size_t)D_IN * E_DIM;              // 256 KB

    pack_all_kernel<<<CB_N / 16 + 32, 256, 0, stream>>>(cb, ph, pl, rp, rph, rpl);
    fused_kernel<<<BN / 64, 256, 0, stream>>>(x, rph, rpl, ph, pl, out);
}